// Round 1
// baseline (349.268 us; speedup 1.0000x reference)
//
#include <hip/hip_runtime.h>
#include <hip/hip_bf16.h>
#include <stdint.h>

typedef unsigned short u16;
typedef __bf16 bf16_t;
typedef bf16_t bf16x8 __attribute__((ext_vector_type(8)));
typedef short s16x4 __attribute__((ext_vector_type(4)));
typedef float f32x4 __attribute__((ext_vector_type(4)));

__device__ __forceinline__ u16 f2bf(float f) {
    union { float f; uint32_t i; } v; v.f = f;
    uint32_t i = v.i;
    uint32_t r = (i + 0x7FFFu + ((i >> 16) & 1u)) >> 16;   // RNE
    return (u16)r;
}

// async global->LDS, 16B per lane; LDS dest = wave-uniform base + lane*16
__device__ __forceinline__ void gload_lds16(const u16* g, u16* l) {
    auto gp = (const __attribute__((address_space(1))) void*)g;
    auto lp = (__attribute__((address_space(3))) void*)(uintptr_t)l;
    __builtin_amdgcn_global_load_lds(gp, lp, 16, 0, 0);
}

// ---------------------------------------------------------------------------
// fp32 -> bf16 bulk convert (x activations). n4 = count of float4 groups.
// ---------------------------------------------------------------------------
__global__ void convert_f32_bf16_kernel(const float* __restrict__ src,
                                        u16* __restrict__ dst, int n4) {
    int i = blockIdx.x * blockDim.x + threadIdx.x;
    if (i < n4) {
        float4 v = ((const float4*)src)[i];
        ushort4 o;
        o.x = f2bf(v.x); o.y = f2bf(v.y); o.z = f2bf(v.z); o.w = f2bf(v.w);
        ((ushort4*)dst)[i] = o;
    }
}

// ---------------------------------------------------------------------------
// W_qk [768][1536] col c = h*128 + dd*2 + qk -> Wqkt row r = qk*768 + h*64 + dd.
// Q rows (r<768) pre-scaled by 1/sqrt(64)=0.125 (exact in bf16).
// ---------------------------------------------------------------------------
__global__ void transpose_qk_kernel(const float* __restrict__ W, const float* __restrict__ b,
                                    u16* __restrict__ Wt, float* __restrict__ bp) {
    int r = blockIdx.x;                 // 0..1535
    int qk = (r >= 768) ? 1 : 0;
    int hd = r - qk * 768;
    int c = (hd >> 6) * 128 + (hd & 63) * 2 + qk;
    float s = qk ? 1.0f : 0.125f;
    for (int k = threadIdx.x; k < 768; k += 256)
        Wt[r * 768 + k] = f2bf(s * W[k * 1536 + c]);
    if (threadIdx.x == 0) bp[r] = s * b[c];
}

// square 768x768 transpose: Wt[n][k] = bf16(W[k][n])
__global__ void transpose_sq_kernel(const float* __restrict__ W, u16* __restrict__ Wt) {
    int n = blockIdx.x;                 // 0..767
    for (int k = threadIdx.x; k < 768; k += 256)
        Wt[n * 768 + k] = f2bf(W[k * 768 + n]);
}

// ---------------------------------------------------------------------------
// bf16 MFMA GEMM, BK=64 (32 MFMAs per barrier), global_load_lds staging,
// 8-seg XOR-swizzled LDS rows ([128][64] u16, phys seg = logical ^ (row&7)).
// C = A[M][K] * Bt[N][K]^T + bias[N].
// MODE 1: f32 out, SWAPPED -> float4 stores to Cout[t][f].
// MODE 2: QK per-head split, SWAPPED -> ushort4 stores to Qp/Kp[b][h][n][64].
// MODE 3: V per-head transposed, UNSWAPPED -> ushort4 stores to Vp[b][h][dv][n].
// ---------------------------------------------------------------------------
template<int MODE>
__global__ __launch_bounds__(256)
void gemm_bt_kernel(const u16* __restrict__ A, const u16* __restrict__ Bt,
                    const float* __restrict__ bias, void* __restrict__ Cout,
                    void* __restrict__ Cout2, int M, int N, int K) {
    __shared__ __attribute__((aligned(16))) u16 As[128 * 64];
    __shared__ __attribute__((aligned(16))) u16 Bs[128 * 64];

    const int tid  = threadIdx.x;
    const int lane = tid & 63;
    const int wave = tid >> 6;
    const int l16  = lane & 15;
    const int quad = lane >> 4;
    const int m0 = blockIdx.y * 128;
    const int n0 = blockIdx.x * 128;
    const int wm = (wave & 1) * 64;
    const int wn = (wave >> 1) * 64;

    f32x4 acc[4][4];
#pragma unroll
    for (int i = 0; i < 4; i++)
#pragma unroll
        for (int j = 0; j < 4; j++) acc[i][j] = (f32x4){0.f, 0.f, 0.f, 0.f};

    // staging: call c covers rows c*32..c*32+31; wave w handles rows c*32+w*8+(lane>>3),
    // phys seg = lane&7, global seg = (lane&7) ^ (lane>>3)  (= phys ^ (row&7)).
    const int rs   = lane >> 3;                 // 0..7
    const int gseg = (lane & 7) ^ rs;
    const u16* Ag[4]; const u16* Bg[4];
#pragma unroll
    for (int c = 0; c < 4; c++) {
        Ag[c] = A  + (size_t)(m0 + c * 32 + wave * 8 + rs) * K + gseg * 8;
        Bg[c] = Bt + (size_t)(n0 + c * 32 + wave * 8 + rs) * K + gseg * 8;
    }
    u16* AsW = As + wave * 512;
    u16* BsW = Bs + wave * 512;
    const int sw7 = l16 & 7;                    // frag-row swizzle (row&7 == l16&7)

    for (int k0 = 0; k0 < K; k0 += 64) {
#pragma unroll
        for (int c = 0; c < 4; c++) {
            gload_lds16(Ag[c] + k0, AsW + c * 2048);
            gload_lds16(Bg[c] + k0, BsW + c * 2048);
        }
        __syncthreads();

        bf16x8 af[4][2], bfr[4][2];
#pragma unroll
        for (int i = 0; i < 4; i++) {
#pragma unroll
            for (int h = 0; h < 2; h++) {
                af[i][h]  = *(const bf16x8*)&As[(wm + i * 16 + l16) * 64 +
                                                (((h * 4 + quad) ^ sw7) * 8)];
                bfr[i][h] = *(const bf16x8*)&Bs[(wn + i * 16 + l16) * 64 +
                                                (((h * 4 + quad) ^ sw7) * 8)];
            }
        }
#pragma unroll
        for (int i = 0; i < 4; i++)
#pragma unroll
            for (int j = 0; j < 4; j++) {
#pragma unroll
                for (int h = 0; h < 2; h++) {
                    if constexpr (MODE == 3)
                        acc[i][j] = __builtin_amdgcn_mfma_f32_16x16x32_bf16(af[i][h], bfr[j][h], acc[i][j], 0, 0, 0);
                    else  // swapped: D rows = features, cols = tokens
                        acc[i][j] = __builtin_amdgcn_mfma_f32_16x16x32_bf16(bfr[j][h], af[i][h], acc[i][j], 0, 0, 0);
                }
            }
        __syncthreads();
    }

    if constexpr (MODE == 3) {
        // D row = token quad*4+r, col = feature l16 per 16x16 tile.
#pragma unroll
        for (int j = 0; j < 4; j++) {
            int cnb = n0 + wn + j * 16;
            int h   = cnb >> 6;
            int dv  = (cnb & 63) + l16;
            float bv = bias[cnb + l16];
#pragma unroll
            for (int i = 0; i < 4; i++) {
                int cm = m0 + wm + i * 16 + quad * 4;
                int bb = cm >> 10, n = cm & 1023;
                ushort4 o;
                o.x = f2bf(acc[i][j][0] + bv);
                o.y = f2bf(acc[i][j][1] + bv);
                o.z = f2bf(acc[i][j][2] + bv);
                o.w = f2bf(acc[i][j][3] + bv);
                *(ushort4*)&((u16*)Cout)[((size_t)((bb * 12 + h) * 64 + dv)) * 1024 + n] = o;
            }
        }
    } else {
        // swapped: D row = feature f0+r (f0 = n0+wn+j*16+quad*4), col = token.
#pragma unroll
        for (int j = 0; j < 4; j++) {
            int f0 = n0 + wn + j * 16 + quad * 4;
            float4 bv = *(const float4*)&bias[f0];
            if constexpr (MODE == 2) {
                int qk = f0 >= 768;
                int hd = f0 - qk * 768;
                int h  = hd >> 6;
                int d0 = hd & 63;
                u16* dst = (u16*)(qk ? Cout2 : Cout);
#pragma unroll
                for (int i = 0; i < 4; i++) {
                    int t = m0 + wm + i * 16 + l16;
                    int bb = t >> 10, n = t & 1023;
                    ushort4 o;
                    o.x = f2bf(acc[i][j][0] + bv.x);
                    o.y = f2bf(acc[i][j][1] + bv.y);
                    o.z = f2bf(acc[i][j][2] + bv.z);
                    o.w = f2bf(acc[i][j][3] + bv.w);
                    *(ushort4*)&dst[((size_t)((bb * 12 + h) * 1024 + n)) * 64 + d0] = o;
                }
            } else {   // MODE 1: fp32 out [t][f]
#pragma unroll
                for (int i = 0; i < 4; i++) {
                    int t = m0 + wm + i * 16 + l16;
                    float4 o;
                    o.x = acc[i][j][0] + bv.x;
                    o.y = acc[i][j][1] + bv.y;
                    o.z = acc[i][j][2] + bv.z;
                    o.w = acc[i][j][3] + bv.w;
                    *(float4*)&((float*)Cout)[(size_t)t * N + f0] = o;
                }
            }
        }
    }
}

// ---------------------------------------------------------------------------
// MFMA flash attention v5: 512-thread blocks, grid (4,192); wave owns 32 q.
// PV now full-rate 16x16x32 with permuted key-slot mapping (slots 0-3 =
// keys 32jp+quad*4+{0..3}, slots 4-7 = keys 32jp+16+quad*4+{0..3}; valid
// since sum over k is order-agnostic and A/B frags use the same mapping).
// ---------------------------------------------------------------------------
__global__ __launch_bounds__(512)
void attention_mfma_kernel(const u16* __restrict__ Qp, const u16* __restrict__ Kp,
                           const u16* __restrict__ Vp, u16* __restrict__ attout) {
    __shared__ __attribute__((aligned(16))) u16 Ks[64 * 64];   // [key][d], swizzled
    __shared__ __attribute__((aligned(16))) u16 Vs[64 * 64];   // [dv][key], swizzled

    const int tid  = threadIdx.x;
    const int wave = tid >> 6;          // 0..7
    const int lane = tid & 63;
    const int l16  = lane & 15;
    const int quad = lane >> 4;
    const int bh = blockIdx.y;          // 0..191 == head
    const int b  = bh / 12, h = bh % 12;
    const int q0 = blockIdx.x * 256 + wave * 32;

    const u16* Qhead = Qp + (size_t)bh * 1024 * 64;
    const u16* Khead = Kp + (size_t)bh * 1024 * 64;
    const u16* Vhead = Vp + (size_t)bh * 64 * 1024;

    // Q B-fragments
    bf16x8 qf[2][2];
#pragma unroll
    for (int qb = 0; qb < 2; qb++) {
        const u16* qrow = Qhead + (size_t)(q0 + qb * 16 + l16) * 64;
        qf[qb][0] = *(const bf16x8*)(qrow + quad * 8);
        qf[qb][1] = *(const bf16x8*)(qrow + 32 + quad * 8);
    }

    f32x4 oacc[2][4];
#pragma unroll
    for (int qb = 0; qb < 2; qb++)
#pragma unroll
        for (int db = 0; db < 4; db++) oacc[qb][db] = (f32x4){0.f, 0.f, 0.f, 0.f};
    float l_part[2] = {0.f, 0.f};

    const int srow = tid >> 3;                  // 0..63
    const int gseg = (tid & 7) ^ (srow & 7);
    u16* KsW = Ks + wave * 512;
    u16* VsW = Vs + wave * 512;
    const int sw7 = l16 & 7;

    for (int kt = 0; kt < 1024; kt += 64) {
        gload_lds16(Khead + (size_t)(kt + srow) * 64 + gseg * 8, KsW);
        gload_lds16(Vhead + (size_t)srow * 1024 + kt + gseg * 8, VsW);
        __syncthreads();

        // --- S^T per q-block, exp, P-frags (packed for K=32 PV) ---
        union { uint32_t u[4]; bf16x8 v; } pf8[2][2];   // [qb][jp]
        {
            bf16x8 kf[4][2];
#pragma unroll
            for (int jb = 0; jb < 4; jb++) {
#pragma unroll
                for (int hf = 0; hf < 2; hf++)
                    kf[jb][hf] = *(const bf16x8*)&Ks[(jb * 16 + l16) * 64 +
                                                     (((hf * 4 + quad) ^ sw7) * 8)];
            }
#pragma unroll
            for (int qb = 0; qb < 2; qb++) {
#pragma unroll
                for (int jb = 0; jb < 4; jb++) {
                    f32x4 st = (f32x4){0.f, 0.f, 0.f, 0.f};
                    st = __builtin_amdgcn_mfma_f32_16x16x32_bf16(kf[jb][0], qf[qb][0], st, 0, 0, 0);
                    st = __builtin_amdgcn_mfma_f32_16x16x32_bf16(kf[jb][1], qf[qb][1], st, 0, 0, 0);
                    float e0 = __expf(st[0]), e1 = __expf(st[1]);
                    float e2 = __expf(st[2]), e3 = __expf(st[3]);
                    l_part[qb] += (e0 + e1) + (e2 + e3);
                    union { __hip_bfloat162 h2; uint32_t u; } c0, c1;
                    c0.h2 = __float22bfloat162_rn(make_float2(e0, e1));
                    c1.h2 = __float22bfloat162_rn(make_float2(e2, e3));
                    pf8[qb][jb >> 1].u[(jb & 1) * 2 + 0] = c0.u;
                    pf8[qb][jb >> 1].u[(jb & 1) * 2 + 1] = c1.u;
                }
            }
        }

        // --- O += P V (full-rate 16x16x32, permuted key slots) ---
#pragma unroll
        for (int db = 0; db < 4; db++) {
#pragma unroll
            for (int jp = 0; jp < 2; jp++) {
                // slots 0-3: keys 32jp+quad*4+..; slots 4-7: keys 32jp+16+quad*4+..
                union { s16x4 h[2]; bf16x8 v; } vb8;
                int glo = 4 * jp + (quad >> 1);
                int ghi = glo + 2;
                vb8.h[0] = *(const s16x4*)&Vs[(db * 16 + l16) * 64 +
                                              ((glo ^ sw7) * 8) + (quad & 1) * 4];
                vb8.h[1] = *(const s16x4*)&Vs[(db * 16 + l16) * 64 +
                                              ((ghi ^ sw7) * 8) + (quad & 1) * 4];
#pragma unroll
                for (int qb = 0; qb < 2; qb++)
                    oacc[qb][db] = __builtin_amdgcn_mfma_f32_16x16x32_bf16(
                        pf8[qb][jp].v, vb8.v, oacc[qb][db], 0, 0, 0);
            }
        }
        __syncthreads();
    }

    // --- final l reduction + normalize + store ---
#pragma unroll
    for (int qb = 0; qb < 2; qb++) {
        float l = l_part[qb];
        l += __shfl_xor(l, 16);
        l += __shfl_xor(l, 32);
        float linv[4];
#pragma unroll
        for (int r = 0; r < 4; r++)
            linv[r] = 1.0f / __shfl(l, quad * 4 + r);
        u16* orow = attout + (size_t)(b * 1024 + q0 + qb * 16 + quad * 4) * 768 + h * 64 + l16;
#pragma unroll
        for (int db = 0; db < 4; db++)
#pragma unroll
            for (int r = 0; r < 4; r++)
                orow[(size_t)r * 768 + db * 16] = f2bf(oacc[qb][db][r] * linv[r]);
    }
}

// ---------------------------------------------------------------------------
extern "C" void kernel_launch(void* const* d_in, const int* in_sizes, int n_in,
                              void* d_out, int out_size, void* d_ws, size_t ws_size,
                              hipStream_t stream) {
    const float* x      = (const float*)d_in[0];
    const float* W_qk   = (const float*)d_in[1];
    const float* b_qk   = (const float*)d_in[2];
    const float* W_v    = (const float*)d_in[3];
    const float* b_v    = (const float*)d_in[4];
    const float* W_proj = (const float*)d_in[5];
    const float* b_proj = (const float*)d_in[6];
    float* out = (float*)d_out;

    char* ws = (char*)d_ws;
    size_t off = 0;
    auto alloc = [&](size_t bytes) { void* p = ws + off; off += (bytes + 255) & ~255ull; return p; };
    u16*   xb     = (u16*)alloc((size_t)16384 * 768 * 2);
    u16*   Wqkt   = (u16*)alloc((size_t)1536 * 768 * 2);
    float* bqkp   = (float*)alloc(1536 * 4);
    u16*   Wvt    = (u16*)alloc((size_t)768 * 768 * 2);
    u16*   Wprojt = (u16*)alloc((size_t)768 * 768 * 2);
    u16*   Qp     = (u16*)alloc((size_t)16384 * 768 * 2);
    u16*   Kp     = (u16*)alloc((size_t)16384 * 768 * 2);
    u16*   Vp     = (u16*)alloc((size_t)16384 * 768 * 2);
    u16*   attout = (u16*)alloc((size_t)16384 * 768 * 2);

    convert_f32_bf16_kernel<<<12288, 256, 0, stream>>>(x, xb, 3145728);
    transpose_qk_kernel<<<1536, 256, 0, stream>>>(W_qk, b_qk, Wqkt, bqkp);
    transpose_sq_kernel<<<768, 256, 0, stream>>>(W_v, Wvt);
    transpose_sq_kernel<<<768, 256, 0, stream>>>(W_proj, Wprojt);

    // QK projection -> Qp/Kp per-head [b][h][n][64] (Q pre-scaled by 0.125)
    gemm_bt_kernel<2><<<dim3(12, 128), 256, 0, stream>>>(xb, Wqkt, bqkp, Qp, Kp, 16384, 1536, 768);
    // V projection -> Vp per-head transposed [b][h][dv][n]
    gemm_bt_kernel<3><<<dim3(6, 128), 256, 0, stream>>>(xb, Wvt, b_v, Vp, nullptr, 16384, 768, 768);
    // attention -> attout (bf16, [token][768])
    attention_mfma_kernel<<<dim3(4, 192), 512, 0, stream>>>(Qp, Kp, Vp, attout);
    // output projection -> d_out (fp32)
    gemm_bt_kernel<1><<<dim3(6, 128), 256, 0, stream>>>(attout, Wprojt, b_proj, out, nullptr, 16384, 768, 768);
}

// Round 3
// 326.179 us; speedup vs baseline: 1.0708x; 1.0708x over previous
//
#include <hip/hip_runtime.h>
#include <hip/hip_bf16.h>
#include <stdint.h>

typedef unsigned short u16;
typedef __bf16 bf16_t;
typedef bf16_t bf16x8 __attribute__((ext_vector_type(8)));
typedef short s16x4 __attribute__((ext_vector_type(4)));
typedef float f32x4 __attribute__((ext_vector_type(4)));

__device__ __forceinline__ u16 f2bf(float f) {
    union { float f; uint32_t i; } v; v.f = f;
    uint32_t i = v.i;
    uint32_t r = (i + 0x7FFFu + ((i >> 16) & 1u)) >> 16;   // RNE
    return (u16)r;
}

// async global->LDS, 16B per lane; LDS dest = wave-uniform base + lane*16
__device__ __forceinline__ void gload_lds16(const u16* g, u16* l) {
    auto gp = (const __attribute__((address_space(1))) void*)g;
    auto lp = (__attribute__((address_space(3))) void*)(uintptr_t)l;
    __builtin_amdgcn_global_load_lds(gp, lp, 16, 0, 0);
}

// ---------------------------------------------------------------------------
// fp32 -> bf16 bulk convert (x activations). n4 = count of float4 groups.
// ---------------------------------------------------------------------------
__global__ void convert_f32_bf16_kernel(const float* __restrict__ src,
                                        u16* __restrict__ dst, int n4) {
    int i = blockIdx.x * blockDim.x + threadIdx.x;
    if (i < n4) {
        float4 v = ((const float4*)src)[i];
        ushort4 o;
        o.x = f2bf(v.x); o.y = f2bf(v.y); o.z = f2bf(v.z); o.w = f2bf(v.w);
        ((ushort4*)dst)[i] = o;
    }
}

// ---------------------------------------------------------------------------
// W_qk [768][1536] col c = h*128 + dd*2 + qk -> Wqkt row r = qk*768 + h*64 + dd.
// Q rows (r<768) pre-scaled by 1/sqrt(64)=0.125 (exact in bf16).
// ---------------------------------------------------------------------------
__global__ void transpose_qk_kernel(const float* __restrict__ W, const float* __restrict__ b,
                                    u16* __restrict__ Wt, float* __restrict__ bp) {
    int r = blockIdx.x;                 // 0..1535
    int qk = (r >= 768) ? 1 : 0;
    int hd = r - qk * 768;
    int c = (hd >> 6) * 128 + (hd & 63) * 2 + qk;
    float s = qk ? 1.0f : 0.125f;
    for (int k = threadIdx.x; k < 768; k += 256)
        Wt[r * 768 + k] = f2bf(s * W[k * 1536 + c]);
    if (threadIdx.x == 0) bp[r] = s * b[c];
}

// square 768x768 transpose: Wt[n][k] = bf16(W[k][n])
__global__ void transpose_sq_kernel(const float* __restrict__ W, u16* __restrict__ Wt) {
    int n = blockIdx.x;                 // 0..767
    for (int k = threadIdx.x; k < 768; k += 256)
        Wt[n * 768 + k] = f2bf(W[k * 768 + n]);
}

// ---------------------------------------------------------------------------
// bf16 MFMA GEMM, BK=64 (32 MFMAs per barrier), global_load_lds staging,
// 8-seg XOR-swizzled LDS rows ([128][64] u16, phys seg = logical ^ (row&7)).
// 1D grid with XCD-chunked swizzle (grid % 8 == 0 required).
// C = A[M][K] * Bt[N][K]^T + bias[N].
// MODE 1: f32 out, SWAPPED -> float4 stores to Cout[t][f].
// MODE 2: QK per-head split, SWAPPED -> ushort4 stores to Qp/Kp[b][h][n][64].
// MODE 3: V per-head transposed, UNSWAPPED -> ushort4 stores to Vp[b][h][dv][n].
// ---------------------------------------------------------------------------
template<int MODE>
__global__ __launch_bounds__(256)
void gemm_bt_kernel(const u16* __restrict__ A, const u16* __restrict__ Bt,
                    const float* __restrict__ bias, void* __restrict__ Cout,
                    void* __restrict__ Cout2, int M, int N, int K) {
    __shared__ __attribute__((aligned(16))) u16 As[128 * 64];
    __shared__ __attribute__((aligned(16))) u16 Bs[128 * 64];

    const int tid  = threadIdx.x;
    const int lane = tid & 63;
    const int wave = tid >> 6;
    const int l16  = lane & 15;
    const int quad = lane >> 4;
    // XCD-chunked block swizzle: XCD k owns a contiguous chunk of tiles.
    const int nxt = N >> 7;
    const int cpx = (int)gridDim.x >> 3;
    const int swz = ((int)blockIdx.x & 7) * cpx + ((int)blockIdx.x >> 3);
    const int m0 = (swz / nxt) * 128;
    const int n0 = (swz % nxt) * 128;
    const int wm = (wave & 1) * 64;
    const int wn = (wave >> 1) * 64;

    f32x4 acc[4][4];
#pragma unroll
    for (int i = 0; i < 4; i++)
#pragma unroll
        for (int j = 0; j < 4; j++) acc[i][j] = (f32x4){0.f, 0.f, 0.f, 0.f};

    // staging: call c covers rows c*32..c*32+31; wave w handles rows c*32+w*8+(lane>>3),
    // phys seg = lane&7, global seg = (lane&7) ^ (lane>>3)  (= phys ^ (row&7)).
    const int rs   = lane >> 3;                 // 0..7
    const int gseg = (lane & 7) ^ rs;
    const u16* Ag[4]; const u16* Bg[4];
#pragma unroll
    for (int c = 0; c < 4; c++) {
        Ag[c] = A  + (size_t)(m0 + c * 32 + wave * 8 + rs) * K + gseg * 8;
        Bg[c] = Bt + (size_t)(n0 + c * 32 + wave * 8 + rs) * K + gseg * 8;
    }
    u16* AsW = As + wave * 512;
    u16* BsW = Bs + wave * 512;
    const int sw7 = l16 & 7;                    // frag-row swizzle (row&7 == l16&7)

    for (int k0 = 0; k0 < K; k0 += 64) {
#pragma unroll
        for (int c = 0; c < 4; c++) {
            gload_lds16(Ag[c] + k0, AsW + c * 2048);
            gload_lds16(Bg[c] + k0, BsW + c * 2048);
        }
        __syncthreads();

        bf16x8 af[4][2], bfr[4][2];
#pragma unroll
        for (int i = 0; i < 4; i++) {
#pragma unroll
            for (int h = 0; h < 2; h++) {
                af[i][h]  = *(const bf16x8*)&As[(wm + i * 16 + l16) * 64 +
                                                (((h * 4 + quad) ^ sw7) * 8)];
                bfr[i][h] = *(const bf16x8*)&Bs[(wn + i * 16 + l16) * 64 +
                                                (((h * 4 + quad) ^ sw7) * 8)];
            }
        }
#pragma unroll
        for (int i = 0; i < 4; i++)
#pragma unroll
            for (int j = 0; j < 4; j++) {
#pragma unroll
                for (int h = 0; h < 2; h++) {
                    if constexpr (MODE == 3)
                        acc[i][j] = __builtin_amdgcn_mfma_f32_16x16x32_bf16(af[i][h], bfr[j][h], acc[i][j], 0, 0, 0);
                    else  // swapped: D rows = features, cols = tokens
                        acc[i][j] = __builtin_amdgcn_mfma_f32_16x16x32_bf16(bfr[j][h], af[i][h], acc[i][j], 0, 0, 0);
                }
            }
        __syncthreads();
    }

    if constexpr (MODE == 3) {
        // D row = token quad*4+r, col = feature l16 per 16x16 tile.
#pragma unroll
        for (int j = 0; j < 4; j++) {
            int cnb = n0 + wn + j * 16;
            int h   = cnb >> 6;
            int dv  = (cnb & 63) + l16;
            float bv = bias[cnb + l16];
#pragma unroll
            for (int i = 0; i < 4; i++) {
                int cm = m0 + wm + i * 16 + quad * 4;
                int bb = cm >> 10, n = cm & 1023;
                ushort4 o;
                o.x = f2bf(acc[i][j][0] + bv);
                o.y = f2bf(acc[i][j][1] + bv);
                o.z = f2bf(acc[i][j][2] + bv);
                o.w = f2bf(acc[i][j][3] + bv);
                *(ushort4*)&((u16*)Cout)[((size_t)((bb * 12 + h) * 64 + dv)) * 1024 + n] = o;
            }
        }
    } else {
        // swapped: D row = feature f0+r (f0 = n0+wn+j*16+quad*4), col = token.
#pragma unroll
        for (int j = 0; j < 4; j++) {
            int f0 = n0 + wn + j * 16 + quad * 4;
            float4 bv = *(const float4*)&bias[f0];
            if constexpr (MODE == 2) {
                int qk = f0 >= 768;
                int hd = f0 - qk * 768;
                int h  = hd >> 6;
                int d0 = hd & 63;
                u16* dst = (u16*)(qk ? Cout2 : Cout);
#pragma unroll
                for (int i = 0; i < 4; i++) {
                    int t = m0 + wm + i * 16 + l16;
                    int bb = t >> 10, n = t & 1023;
                    ushort4 o;
                    o.x = f2bf(acc[i][j][0] + bv.x);
                    o.y = f2bf(acc[i][j][1] + bv.y);
                    o.z = f2bf(acc[i][j][2] + bv.z);
                    o.w = f2bf(acc[i][j][3] + bv.w);
                    *(ushort4*)&dst[((size_t)((bb * 12 + h) * 1024 + n)) * 64 + d0] = o;
                }
            } else {   // MODE 1: fp32 out [t][f]
#pragma unroll
                for (int i = 0; i < 4; i++) {
                    int t = m0 + wm + i * 16 + l16;
                    float4 o;
                    o.x = acc[i][j][0] + bv.x;
                    o.y = acc[i][j][1] + bv.y;
                    o.z = acc[i][j][2] + bv.z;
                    o.w = acc[i][j][3] + bv.w;
                    *(float4*)&((float*)Cout)[(size_t)t * N + f0] = o;
                }
            }
        }
    }
}

// ---------------------------------------------------------------------------
// MFMA flash attention v6b: 512-thread blocks, 1D grid 768 (XCD-chunked:
// 24 whole heads per XCD -> K/V fetched once per XCD L2).
// Double-buffered K/V staging (T3 2-phase): one barrier per tile; next
// tile's global_load_lds issued right after the barrier so the current
// tile's compute hides the staging latency. Arithmetic is bit-identical
// to the single-buffer version (same MFMA order, same __expf).
// s_setprio(1) around MFMA clusters (phase-split waves -> T5 applies).
// ---------------------------------------------------------------------------
__global__ __launch_bounds__(512)
void attention_mfma_kernel(const u16* __restrict__ Qp, const u16* __restrict__ Kp,
                           const u16* __restrict__ Vp, u16* __restrict__ attout) {
    __shared__ __attribute__((aligned(16))) u16 Ks[2][64 * 64];   // [key][d], swizzled
    __shared__ __attribute__((aligned(16))) u16 Vs[2][64 * 64];   // [dv][key], swizzled

    const int tid  = threadIdx.x;
    const int wave = tid >> 6;          // 0..7
    const int lane = tid & 63;
    const int l16  = lane & 15;
    const int quad = lane >> 4;
    // XCD-chunked swizzle over 768 blocks: swz = head*4 + qchunk
    const int flat = blockIdx.x;
    const int swz  = (flat & 7) * 96 + (flat >> 3);
    const int bh   = swz >> 2;          // 0..191 == head
    const int b    = bh / 12, h = bh % 12;
    const int q0   = (swz & 3) * 256 + wave * 32;

    const u16* Qhead = Qp + (size_t)bh * 1024 * 64;
    const u16* Khead = Kp + (size_t)bh * 1024 * 64;
    const u16* Vhead = Vp + (size_t)bh * 64 * 1024;

    // Q B-fragments
    bf16x8 qf[2][2];
#pragma unroll
    for (int qb = 0; qb < 2; qb++) {
        const u16* qrow = Qhead + (size_t)(q0 + qb * 16 + l16) * 64;
        qf[qb][0] = *(const bf16x8*)(qrow + quad * 8);
        qf[qb][1] = *(const bf16x8*)(qrow + 32 + quad * 8);
    }

    f32x4 oacc[2][4];
#pragma unroll
    for (int qb = 0; qb < 2; qb++)
#pragma unroll
        for (int db = 0; db < 4; db++) oacc[qb][db] = (f32x4){0.f, 0.f, 0.f, 0.f};
    float l_part[2] = {0.f, 0.f};

    const int srow = tid >> 3;                  // 0..63
    const int gseg = (tid & 7) ^ (srow & 7);
    const u16* Kg = Khead + (size_t)srow * 64 + gseg * 8;    // + t*4096 per tile
    const u16* Vg = Vhead + (size_t)srow * 1024 + gseg * 8;  // + t*64 per tile
    const int sw7 = l16 & 7;

    // prologue: stage tile 0 into buffer 0
    gload_lds16(Kg, &Ks[0][wave * 512]);
    gload_lds16(Vg, &Vs[0][wave * 512]);

    int cur = 0;
    for (int t = 0; t < 16; ++t) {
        __syncthreads();   // own vmcnt(0)+lgkmcnt(0) then barrier: tile t ready, buf^1 free
        if (t < 15) {      // issue next tile's staging; compute below hides its latency
            gload_lds16(Kg + (t + 1) * 4096, &Ks[cur ^ 1][wave * 512]);
            gload_lds16(Vg + (t + 1) * 64,   &Vs[cur ^ 1][wave * 512]);
        }
        const u16* Ksc = Ks[cur];
        const u16* Vsc = Vs[cur];

        // --- S^T per q-block, exp, P-frags (packed for K=32 PV) ---
        union { uint32_t u[4]; bf16x8 v; } pf8[2][2];   // [qb][jp]
        {
            bf16x8 kf[4][2];
#pragma unroll
            for (int jb = 0; jb < 4; jb++) {
#pragma unroll
                for (int hf = 0; hf < 2; hf++)
                    kf[jb][hf] = *(const bf16x8*)&Ksc[(jb * 16 + l16) * 64 +
                                                      (((hf * 4 + quad) ^ sw7) * 8)];
            }
#pragma unroll
            for (int qb = 0; qb < 2; qb++) {
#pragma unroll
                for (int jb = 0; jb < 4; jb++) {
                    f32x4 st = (f32x4){0.f, 0.f, 0.f, 0.f};
                    __builtin_amdgcn_s_setprio(1);
                    st = __builtin_amdgcn_mfma_f32_16x16x32_bf16(kf[jb][0], qf[qb][0], st, 0, 0, 0);
                    st = __builtin_amdgcn_mfma_f32_16x16x32_bf16(kf[jb][1], qf[qb][1], st, 0, 0, 0);
                    __builtin_amdgcn_s_setprio(0);
                    float e0 = __expf(st[0]), e1 = __expf(st[1]);
                    float e2 = __expf(st[2]), e3 = __expf(st[3]);
                    l_part[qb] += (e0 + e1) + (e2 + e3);
                    union { __hip_bfloat162 h2; uint32_t u; } c0, c1;
                    c0.h2 = __float22bfloat162_rn(make_float2(e0, e1));
                    c1.h2 = __float22bfloat162_rn(make_float2(e2, e3));
                    pf8[qb][jb >> 1].u[(jb & 1) * 2 + 0] = c0.u;
                    pf8[qb][jb >> 1].u[(jb & 1) * 2 + 1] = c1.u;
                }
            }
        }

        // --- O += P V (full-rate 16x16x32, permuted key slots) ---
        __builtin_amdgcn_s_setprio(1);
#pragma unroll
        for (int db = 0; db < 4; db++) {
#pragma unroll
            for (int jp = 0; jp < 2; jp++) {
                // slots 0-3: keys 32jp+quad*4+..; slots 4-7: keys 32jp+16+quad*4+..
                union { s16x4 h[2]; bf16x8 v; } vb8;
                int glo = 4 * jp + (quad >> 1);
                int ghi = glo + 2;
                vb8.h[0] = *(const s16x4*)&Vsc[(db * 16 + l16) * 64 +
                                               ((glo ^ sw7) * 8) + (quad & 1) * 4];
                vb8.h[1] = *(const s16x4*)&Vsc[(db * 16 + l16) * 64 +
                                               ((ghi ^ sw7) * 8) + (quad & 1) * 4];
#pragma unroll
                for (int qb = 0; qb < 2; qb++)
                    oacc[qb][db] = __builtin_amdgcn_mfma_f32_16x16x32_bf16(
                        pf8[qb][jp].v, vb8.v, oacc[qb][db], 0, 0, 0);
            }
        }
        __builtin_amdgcn_s_setprio(0);
        cur ^= 1;
    }

    // --- final l reduction + normalize + store ---
#pragma unroll
    for (int qb = 0; qb < 2; qb++) {
        float l = l_part[qb];
        l += __shfl_xor(l, 16);
        l += __shfl_xor(l, 32);
        float linv[4];
#pragma unroll
        for (int r = 0; r < 4; r++)
            linv[r] = 1.0f / __shfl(l, quad * 4 + r);
        u16* orow = attout + (size_t)(b * 1024 + q0 + qb * 16 + quad * 4) * 768 + h * 64 + l16;
#pragma unroll
        for (int db = 0; db < 4; db++)
#pragma unroll
            for (int r = 0; r < 4; r++)
                orow[(size_t)r * 768 + db * 16] = f2bf(oacc[qb][db][r] * linv[r]);
    }
}

// ---------------------------------------------------------------------------
extern "C" void kernel_launch(void* const* d_in, const int* in_sizes, int n_in,
                              void* d_out, int out_size, void* d_ws, size_t ws_size,
                              hipStream_t stream) {
    const float* x      = (const float*)d_in[0];
    const float* W_qk   = (const float*)d_in[1];
    const float* b_qk   = (const float*)d_in[2];
    const float* W_v    = (const float*)d_in[3];
    const float* b_v    = (const float*)d_in[4];
    const float* W_proj = (const float*)d_in[5];
    const float* b_proj = (const float*)d_in[6];
    float* out = (float*)d_out;

    char* ws = (char*)d_ws;
    size_t off = 0;
    auto alloc = [&](size_t bytes) { void* p = ws + off; off += (bytes + 255) & ~255ull; return p; };
    u16*   xb     = (u16*)alloc((size_t)16384 * 768 * 2);
    u16*   Wqkt   = (u16*)alloc((size_t)1536 * 768 * 2);
    float* bqkp   = (float*)alloc(1536 * 4);
    u16*   Wvt    = (u16*)alloc((size_t)768 * 768 * 2);
    u16*   Wprojt = (u16*)alloc((size_t)768 * 768 * 2);
    u16*   Qp     = (u16*)alloc((size_t)16384 * 768 * 2);
    u16*   Kp     = (u16*)alloc((size_t)16384 * 768 * 2);
    u16*   Vp     = (u16*)alloc((size_t)16384 * 768 * 2);
    u16*   attout = (u16*)alloc((size_t)16384 * 768 * 2);

    convert_f32_bf16_kernel<<<12288, 256, 0, stream>>>(x, xb, 3145728);
    transpose_qk_kernel<<<1536, 256, 0, stream>>>(W_qk, b_qk, Wqkt, bqkp);
    transpose_sq_kernel<<<768, 256, 0, stream>>>(W_v, Wvt);
    transpose_sq_kernel<<<768, 256, 0, stream>>>(W_proj, Wprojt);

    // QK projection -> Qp/Kp per-head [b][h][n][64] (Q pre-scaled by 0.125)
    gemm_bt_kernel<2><<<1536, 256, 0, stream>>>(xb, Wqkt, bqkp, Qp, Kp, 16384, 1536, 768);
    // V projection -> Vp per-head transposed [b][h][dv][n]
    gemm_bt_kernel<3><<<768, 256, 0, stream>>>(xb, Wvt, b_v, Vp, nullptr, 16384, 768, 768);
    // attention -> attout (bf16, [token][768])
    attention_mfma_kernel<<<768, 512, 0, stream>>>(Qp, Kp, Vp, attout);
    // output projection -> d_out (fp32)
    gemm_bt_kernel<1><<<768, 256, 0, stream>>>(attout, Wprojt, b_proj, out, nullptr, 16384, 768, 768);
}